// Round 13
// baseline (220.097 us; speedup 1.0000x reference)
//
#include <hip/hip_runtime.h>
#include <float.h>

#define D    64
#define K    512
#define HW   4096      // 64*64
#define NPIX 131072    // 32*4096
#define KT   16
#define GT_S 2.5e-4f   // s-units gap threshold; el-drop error sigma ~1.5e-5 -> >=8 sigma

// ===== MFMA-path ws layout (bytes) =====
#define OFF_CK    0u          // float ck[512]
#define OFF_CBFH  2048u       // ushort cbfh[64*512] frag-packed
#define OFF_IDX   34211840u   // int idx[NPIX]
#define OFF_CNT   34736128u   // int count
#define OFF_LIST  34736132u   // int list[NPIX]
#define OFF_CKQ   35260420u   // float ckq[512] = -ck/2
#define WS_NEED   35262468u

typedef __attribute__((ext_vector_type(8))) short bf16x8;
typedef __attribute__((ext_vector_type(4))) float f32x4;

__device__ __forceinline__ unsigned short bf16_rne(float f) {
    unsigned u = __float_as_uint(f);
    return (unsigned short)((u + 0x7FFFu + ((u >> 16) & 1u)) >> 16);
}

// ck[k] = numpy sum(cb*cb, axis=0): sequential adds over d, squares pre-rounded.
// ckq[k] = -ck/2. Packs bf16(cb) into fragment layout:
//   pos(tile=k>>4, ks=d>>5, g=(d>>3)&3, n=k&15, j=d&7) = (tile*2+ks)*512 + g*128 + n*8 + j
__global__ void vq_prep_m(const float* __restrict__ cb, float* __restrict__ ck,
                          float* __restrict__ ckq, unsigned short* __restrict__ cbfh,
                          int* __restrict__ count) {
#pragma clang fp contract(off)
    const int k = blockIdx.x * 128 + threadIdx.x;
    if (k == 0) *count = 0;
    float s = 0.f;
    for (int d = 0; d < D; ++d) {
        const float e  = cb[d * K + k];
        const float e2 = e * e;
        s = s + e2;
        const int pos = ((k >> 4) * 2 + (d >> 5)) * 512 + ((d >> 3) & 3) * 128 + (k & 15) * 8 + (d & 7);
        cbfh[pos] = bf16_rne(e);
    }
    ck[k]  = s;
    ckq[k] = -0.5f * s;
}

// MFMA filter v5 = round-9 skeleton (16 px/wave, LDS-staged B, small regs, NO
// spill) + round-10/11 math (s-space, hi/lo x from enc in-register) + el-drop
// (4 MFMA/tile, bh only in LDS).  dot = (xh+xl)*bf16(e); any pixel whose
// best-vs-second s-gap < GT_S goes to the exact-numpy refine.
#define CVT_PAIR(HP, LP, F0, F1) do {                                      \
    asm("v_cvt_pk_bf16_f32 %0, %1, %2" : "=v"(HP) : "v"(F0), "v"(F1));     \
    const float _b0 = __uint_as_float((HP) << 16);                         \
    const float _b1 = __uint_as_float((HP) & 0xffff0000u);                 \
    const float _r0 = (F0) - _b0;                                          \
    const float _r1 = (F1) - _b1;                                          \
    asm("v_cvt_pk_bf16_f32 %0, %1, %2" : "=v"(LP) : "v"(_r0), "v"(_r1));   \
} while (0)

#define LOAD_A(KS, H4, L4) do {                                            \
    const float r0 = ep[(size_t)((KS) * 32 + g * 8 + 0) * HW + hwp];       \
    const float r1 = ep[(size_t)((KS) * 32 + g * 8 + 1) * HW + hwp];       \
    const float r2 = ep[(size_t)((KS) * 32 + g * 8 + 2) * HW + hwp];       \
    const float r3 = ep[(size_t)((KS) * 32 + g * 8 + 3) * HW + hwp];       \
    const float r4 = ep[(size_t)((KS) * 32 + g * 8 + 4) * HW + hwp];       \
    const float r5 = ep[(size_t)((KS) * 32 + g * 8 + 5) * HW + hwp];       \
    const float r6 = ep[(size_t)((KS) * 32 + g * 8 + 6) * HW + hwp];       \
    const float r7 = ep[(size_t)((KS) * 32 + g * 8 + 7) * HW + hwp];       \
    CVT_PAIR(H4.x, L4.x, r0, r1);                                          \
    CVT_PAIR(H4.y, L4.y, r2, r3);                                          \
    CVT_PAIR(H4.z, L4.z, r4, r5);                                          \
    CVT_PAIR(H4.w, L4.w, r6, r7);                                          \
} while (0)

__global__ __launch_bounds__(256) void vq_mfma(const float* __restrict__ enc,
        const unsigned short* __restrict__ cbfh, const float* __restrict__ ckq,
        int* __restrict__ idx, int* __restrict__ count, int* __restrict__ list) {
    __shared__ unsigned short sbh[8192];   // 16 KB: one G-group (8 tiles) of bh frags
    __shared__ float sck[512];             // 2 KB: ckq staged once

    const int t    = threadIdx.x;
    const int lane = t & 63;
    const int wu   = __builtin_amdgcn_readfirstlane(t >> 6);
    const int P0   = blockIdx.x * 64 + wu * 16;
    const int n    = lane & 15;          // A row (pixel) / B col (code) / C col
    const int g    = lane >> 4;          // k-chunk; C rows g*4..g*4+3

    sck[t] = ckq[t];
    sck[t + 256] = ckq[t + 256];

    // A-frags from enc, bf16 hi/lo split in-register (named scalars)
    const float* ep = enc + (size_t)(P0 >> 12) * (D * HW);
    const int hwp = (P0 & 4095) + n;
    uint4 ah0, ah1, al0, al1;
    LOAD_A(0, ah0, al0);
    LOAD_A(1, ah1, al1);

    const f32x4 Z4 = {0.f, 0.f, 0.f, 0.f};
    const char* sb = (const char*)sbh;
    const int rb = g * 256 + n * 16;     // per-lane B base (bytes)

    float b0, b1, b2, b3, c0, c1, c2, c3;
    int i0, i1, i2, i3;
    b0 = b1 = b2 = b3 = -FLT_MAX;
    c0 = c1 = c2 = c3 = -FLT_MAX;
    i0 = i1 = i2 = i3 = 0;

    #pragma unroll 1
    for (int G = 0; G < 4; ++G) {
        __syncthreads();
        {   // stage 8 tiles of bh (16 KB), linear copy, coalesced uint4
            const uint4* srcG = (const uint4*)cbfh + (G << 10);
            uint4* du = (uint4*)sbh;
            du[t]       = srcG[t];
            du[t + 256] = srcG[t + 256];
            du[t + 512] = srcG[t + 512];
            du[t + 768] = srcG[t + 768];
        }
        __syncthreads();

        #pragma unroll
        for (int tl = 0; tl < 8; ++tl) {
            const int tile = G * 8 + tl;
            const bf16x8 bh0 = *(const bf16x8*)(sb + rb + tl * 2048);
            const bf16x8 bh1 = *(const bf16x8*)(sb + rb + tl * 2048 + 1024);
            const float ckv = sck[tile * 16 + n];

            f32x4 p0, p1;
            p0 = __builtin_amdgcn_mfma_f32_16x16x32_bf16(__builtin_bit_cast(bf16x8, al0), bh0, Z4, 0, 0, 0);
            p0 = __builtin_amdgcn_mfma_f32_16x16x32_bf16(__builtin_bit_cast(bf16x8, ah0), bh0, p0, 0, 0, 0);
            p1 = __builtin_amdgcn_mfma_f32_16x16x32_bf16(__builtin_bit_cast(bf16x8, al1), bh1, Z4, 0, 0, 0);
            p1 = __builtin_amdgcn_mfma_f32_16x16x32_bf16(__builtin_bit_cast(bf16x8, ah1), bh1, p1, 0, 0, 0);

            { const float v = (p0[0] + p1[0]) + ckv; const bool gt = v > b0; i0 = gt ? tile : i0; c0 = fmaxf(c0, fminf(b0, v)); b0 = fmaxf(b0, v); }
            { const float v = (p0[1] + p1[1]) + ckv; const bool gt = v > b1; i1 = gt ? tile : i1; c1 = fmaxf(c1, fminf(b1, v)); b1 = fmaxf(b1, v); }
            { const float v = (p0[2] + p1[2]) + ckv; const bool gt = v > b2; i2 = gt ? tile : i2; c2 = fmaxf(c2, fminf(b2, v)); b2 = fmaxf(b2, v); }
            { const float v = (p0[3] + p1[3]) + ckv; const bool gt = v > b3; i3 = gt ? tile : i3; c3 = fmaxf(c3, fminf(b3, v)); b3 = fmaxf(b3, v); }
        }
    }

    // full code index, then merge the 16 lanes (same g = same 4 pixels)
    i0 = i0 * 16 + n; i1 = i1 * 16 + n; i2 = i2 * 16 + n; i3 = i3 * 16 + n;
    #pragma unroll
    for (int off = 1; off < 16; off <<= 1) {
        { const float ob = __shfl_xor(b0, off, 16); const float oc = __shfl_xor(c0, off, 16); const int oi = __shfl_xor(i0, off, 16); const bool gt = ob > b0; c0 = fmaxf(fminf(b0, ob), gt ? oc : c0); i0 = gt ? oi : i0; b0 = fmaxf(b0, ob); }
        { const float ob = __shfl_xor(b1, off, 16); const float oc = __shfl_xor(c1, off, 16); const int oi = __shfl_xor(i1, off, 16); const bool gt = ob > b1; c1 = fmaxf(fminf(b1, ob), gt ? oc : c1); i1 = gt ? oi : i1; b1 = fmaxf(b1, ob); }
        { const float ob = __shfl_xor(b2, off, 16); const float oc = __shfl_xor(c2, off, 16); const int oi = __shfl_xor(i2, off, 16); const bool gt = ob > b2; c2 = fmaxf(fminf(b2, ob), gt ? oc : c2); i2 = gt ? oi : i2; b2 = fmaxf(b2, ob); }
        { const float ob = __shfl_xor(b3, off, 16); const float oc = __shfl_xor(c3, off, 16); const int oi = __shfl_xor(i3, off, 16); const bool gt = ob > b3; c3 = fmaxf(fminf(b3, ob), gt ? oc : c3); i3 = gt ? oi : i3; b3 = fmaxf(b3, ob); }
    }

    if (n == 0) {
        { const int p = P0 + g * 4 + 0; idx[p] = i0; if (b0 - c0 < GT_S) { const int s = atomicAdd(count, 1); list[s] = p; } }
        { const int p = P0 + g * 4 + 1; idx[p] = i1; if (b1 - c1 < GT_S) { const int s = atomicAdd(count, 1); list[s] = p; } }
        { const int p = P0 + g * 4 + 2; idx[p] = i2; if (b2 - c2 < GT_S) { const int s = atomicAdd(count, 1); list[s] = p; } }
        { const int p = P0 + g * 4 + 3; idx[p] = i3; if (b3 - c3 < GT_S) { const int s = atomicAdd(count, 1); list[s] = p; } }
    }
}

// Exact numpy rescore for near-tie pixels; self-computed numpy-exact t1 (proven).
__global__ __launch_bounds__(256) void vq_refine(const float* __restrict__ enc,
        const float* __restrict__ cb, const float* __restrict__ ck,
        const int* __restrict__ count, const int* __restrict__ list,
        int* __restrict__ idx) {
    const int nref = *count;
    const int lane = threadIdx.x & 63;
    const int gw   = (int)((blockIdx.x * blockDim.x + threadIdx.x) >> 6);
    const int nw   = (int)((gridDim.x * blockDim.x) >> 6);
    for (int r = gw; r < nref; r += nw) {
        const int p  = list[r];
        const int b  = p >> 12;
        const int hw = p & 4095;
        const float* xp = enc + (size_t)b * (D * HW) + hw;
        const float xown = xp[(size_t)lane * HW];   // lane holds x[lane]

        // t1: numpy pairwise n=64 path, bit-exact.
        float t1;
        {
#pragma clang fp contract(off)
            const int jl = lane & 7;
            float rj;
            {
                const float v = __shfl(xown, jl);
                rj = v * v;
            }
            #pragma unroll
            for (int i = 1; i < 8; ++i) {
                const float v  = __shfl(xown, i * 8 + jl);
                const float v2 = v * v;
                rj = rj + v2;
            }
            const float a  = rj + __shfl_xor(rj, 1);
            const float bb = a + __shfl_xor(a, 2);
            t1 = bb + __shfl_xor(bb, 4);
        }

        float acc[8];
        #pragma unroll
        for (int j = 0; j < 8; ++j) acc[j] = 0.f;
        const float* cbl = cb + lane * 8;
        #pragma unroll 16
        for (int d = 0; d < D; ++d) {
            const float xd = __shfl(xown, d);
            const float4 q0 = *(const float4*)(cbl + (size_t)d * K);
            const float4 q1 = *(const float4*)(cbl + (size_t)d * K + 4);
            acc[0] = fmaf(xd, q0.x, acc[0]);
            acc[1] = fmaf(xd, q0.y, acc[1]);
            acc[2] = fmaf(xd, q0.z, acc[2]);
            acc[3] = fmaf(xd, q0.w, acc[3]);
            acc[4] = fmaf(xd, q1.x, acc[4]);
            acc[5] = fmaf(xd, q1.y, acc[5]);
            acc[6] = fmaf(xd, q1.z, acc[6]);
            acc[7] = fmaf(xd, q1.w, acc[7]);
        }
        float bv = FLT_MAX;
        int bI = 0x7fffffff;
        #pragma unroll
        for (int j = 0; j < 8; ++j) {
            const float u    = fmaf(-2.0f, acc[j], t1);
            const float dist = u + ck[lane * 8 + j];
            if (dist < bv) { bv = dist; bI = lane * 8 + j; }
        }
        #pragma unroll
        for (int off = 32; off > 0; off >>= 1) {
            const float ov = __shfl_down(bv, off);
            const int   oi = __shfl_down(bI, off);
            if (ov < bv || (ov == bv && oi < bI)) { bv = ov; bI = oi; }
        }
        if (lane == 0) idx[p] = bI;
    }
}

// ===== scalar fallback (round-7, proven 128 us) =====
__global__ void vq_prep_s(const float* __restrict__ cb, float* __restrict__ ck) {
#pragma clang fp contract(off)
    const int k = threadIdx.x;
    float s = 0.f;
    for (int d = 0; d < D; ++d) {
        const float e  = cb[d * K + k];
        const float e2 = e * e;
        s = s + e2;
    }
    ck[k] = s;
}

__global__ __launch_bounds__(256, 8) void vq_main_s(const float* __restrict__ enc,
        const float* __restrict__ cb, const float* __restrict__ ck,
        int* __restrict__ idx) {
    __shared__ float xs[D][64];
    __shared__ float bvs[3][64];
    __shared__ int   bis[3][64];

    const int t    = threadIdx.x;
    const int lane = t & 63;
    const int wu   = __builtin_amdgcn_readfirstlane(t >> 6);
    const int base = blockIdx.x * 64;
    const int b    = base >> 12;
    const int hw0  = base & 4095;
    const float* ep = enc + (size_t)b * (D * HW) + hw0;

    #pragma unroll
    for (int i = 0; i < 16; ++i) {
        const int id  = t + i * 256;
        xs[id >> 6][id & 63] = ep[(size_t)(id >> 6) * HW + (id & 63)];
    }
    __syncthreads();

    float t1;
    {
#pragma clang fp contract(off)
        float r[8];
        #pragma unroll
        for (int j = 0; j < 8; ++j) { const float v = xs[j][lane]; r[j] = v * v; }
        #pragma unroll
        for (int i = 8; i < 64; i += 8) {
            #pragma unroll
            for (int j = 0; j < 8; ++j) {
                const float v = xs[i + j][lane]; const float v2 = v * v; r[j] = r[j] + v2;
            }
        }
        t1 = ((r[0] + r[1]) + (r[2] + r[3])) + ((r[4] + r[5]) + (r[6] + r[7]));
    }

    float best = FLT_MAX;
    int besti  = 0x7fffffff;
    const int kbase = wu * (K / 4);
    #pragma unroll 1
    for (int tt = 0; tt < 8; ++tt) {
        const int k0 = kbase + tt * KT;
        float acc[KT];
        #pragma unroll
        for (int j = 0; j < KT; ++j) acc[j] = 0.f;
        #pragma unroll 8
        for (int d = 0; d < D; ++d) {
            const float xv = xs[d][lane];
            const float* cbrow = cb + d * K + k0;
            #pragma unroll
            for (int j = 0; j < KT; ++j) acc[j] = fmaf(xv, cbrow[j], acc[j]);
        }
        #pragma unroll
        for (int j = 0; j < KT; ++j) {
            const float u    = fmaf(-2.0f, acc[j], t1);
            const float dist = u + ck[k0 + j];
            if (dist < best) { best = dist; besti = k0 + j; }
        }
    }

    if (wu > 0) { bvs[wu - 1][lane] = best; bis[wu - 1][lane] = besti; }
    __syncthreads();
    if (wu == 0) {
        #pragma unroll
        for (int q = 0; q < 3; ++q) {
            const float ov = bvs[q][lane];
            const int   oi = bis[q][lane];
            if (ov < best) { best = ov; besti = oi; }
        }
        idx[base + lane] = besti;
    }
}

__global__ void vq_out(const float* __restrict__ cb, const int* __restrict__ idx,
                       float* __restrict__ out) {
    const int o = (blockIdx.x * 256 + threadIdx.x) * 4;
    const int d = (o >> 12) & 63;
    const int bhw = ((o >> 18) << 12) | (o & 4095);
    const int4 iv = *reinterpret_cast<const int4*>(idx + bhw);
    float4 v;
    v.x = cb[d * K + iv.x];
    v.y = cb[d * K + iv.y];
    v.z = cb[d * K + iv.z];
    v.w = cb[d * K + iv.w];
    *reinterpret_cast<float4*>(out + o) = v;
}

extern "C" void kernel_launch(void* const* d_in, const int* in_sizes, int n_in,
                              void* d_out, int out_size, void* d_ws, size_t ws_size,
                              hipStream_t stream) {
    const float* enc = (const float*)d_in[0];
    const float* cb  = (const float*)d_in[1];
    float* out = (float*)d_out;
    char* ws = (char*)d_ws;

    if (ws_size >= (size_t)WS_NEED) {
        float*          ck   = (float*)(ws + OFF_CK);
        float*          ckq  = (float*)(ws + OFF_CKQ);
        unsigned short* cbfh = (unsigned short*)(ws + OFF_CBFH);
        int*            idx  = (int*)(ws + OFF_IDX);
        int*            cnt  = (int*)(ws + OFF_CNT);
        int*            list = (int*)(ws + OFF_LIST);

        vq_prep_m<<<4, 128, 0, stream>>>(cb, ck, ckq, cbfh, cnt);
        vq_mfma<<<NPIX / 64, 256, 0, stream>>>(enc, cbfh, ckq, idx, cnt, list);
        vq_refine<<<1024, 256, 0, stream>>>(enc, cb, ck, cnt, list, idx);
        vq_out<<<out_size / 1024, 256, 0, stream>>>(cb, idx, out);
    } else {
        float* ck  = (float*)ws;
        int*   idx = (int*)(ws + 2048);
        vq_prep_s<<<1, K, 0, stream>>>(cb, ck);
        vq_main_s<<<NPIX / 64, 256, 0, stream>>>(enc, cb, ck, idx);
        vq_out<<<out_size / 1024, 256, 0, stream>>>(cb, idx, out);
    }
}